// Round 6
// baseline (364.129 us; speedup 1.0000x reference)
//
#include <hip/hip_runtime.h>
#include <math.h>

// ---- problem sizes ----
constexpr int Bz = 32, Vz = 21, Dz = 512, Pz = 64;
constexpr int INz = Dz * Pz;         // 32768
constexpr int OUTz = 720;
constexpr int Ez = 8, Rz = 16, Hz = 256;
constexpr int Mz = Bz * Vz;          // 672
constexpr int Nz = OUTz + Ez * Rz;   // 848
constexpr int Kz = INz;

// ---- OLD fp32-register-staged GEMM tiling (fallback path) ----
constexpr int BM = 128, BN = 128, BK = 32;
constexpr int SPLIT = 16;            // 7*6*16 = 672 blocks
constexpr int KSL = Kz / SPLIT;      // 2048
constexpr int NCH = KSL / BK;        // 64
constexpr int LDA = 36;

// ---- f16 DMA-staged GEMM tiling (fast path) ----
constexpr int BM2 = 256, BN2 = 128, BK2 = 32;
constexpr int SPLIT2 = 32;
constexpr int KSL2 = Kz / SPLIT2;    // 1024
constexpr int NCH2 = KSL2 / BK2;     // 32
constexpr int ABUF = BM2 * BK2;      // 8192 halves = 16 KB
constexpr int BBUF = BN2 * BK2;      // 4096 halves = 8 KB
constexpr int SLOT = ABUF + BBUF;    // 24 KB per ring slot, ring of 3 = 72 KB

// ---- dense-front x-only convert decomposition ----
constexpr int CVNB  = 1344;                 // blocks (= Mz*16/8 exactly)
constexpr int CVCH  = 2048;                 // floats per chunk (8 KB)
constexpr int CVTOT = Mz * (Kz / CVCH);     // 10752 = 1344 * 8 exactly

typedef _Float16 f16x8 __attribute__((ext_vector_type(8)));
typedef __fp16  fp16x2 __attribute__((ext_vector_type(2)));
typedef float f32x4 __attribute__((ext_vector_type(4)));

__device__ __forceinline__ unsigned int cvt2(float a, float b) {
    fp16x2 p = __builtin_amdgcn_cvt_pkrtz(a, b);
    return __builtin_bit_cast(unsigned int, p);
}

__device__ __forceinline__ void barrier_lgkm() {
    asm volatile("s_waitcnt lgkmcnt(0)\n\ts_barrier" ::: "memory");
}

// direct global->LDS DMA, 16 B per lane; LDS dest is wave-uniform base + lane*16
__device__ __forceinline__ void gload16(const _Float16* g, _Float16* l) {
    __builtin_amdgcn_global_load_lds(
        (const __attribute__((address_space(1))) unsigned int*)g,
        (__attribute__((address_space(3))) unsigned int*)l, 16, 0, 0);
}

// ===================== OLD fused GEMM (+pooling) — fallback =====================
template <bool PART>
__global__ __launch_bounds__(256, 3)
void gemm_pool_kernel(const float* __restrict__ x, const float* __restrict__ Wb,
                      const float* __restrict__ lA, float* __restrict__ part,
                      float* __restrict__ C, float* __restrict__ pooled)
{
    __shared__ _Float16 As[2][BM * LDA];
    __shared__ _Float16 Bs[2][BN * LDA];
    __shared__ float plocal[BM][NCH / 2];

    const int id = blockIdx.x;
    const int x8 = id & 7;
    const int k8 = id >> 3;
    const int nt = k8 % 7;
    const int mt = (k8 / 7) % 6;
    const int s  = (k8 / 42) * 8 + x8;

    const int t  = threadIdx.x;
    const int r  = t >> 1;
    const int h  = t & 1;
    const int kbase = s * KSL + h * 16;

    int gm = mt * BM + r;
    const bool mval = (gm < Mz);
    if (!mval) gm = Mz - 1;
    const float* pa = x + (size_t)gm * Kz + kbase;

    int gn = nt * BN + r;
    if (gn >= Nz) gn = Nz - 1;
    const float* pb = (gn < OUTz) ? (Wb + (size_t)gn * Kz + kbase)
                                  : (lA + (size_t)(gn - OUTz) * Kz + kbase);

    const int wave = t >> 6, lane = t & 63;
    const int wr = (wave >> 1) * 64;
    const int wc = (wave & 1) * 64;
    const int fl = lane & 15;
    const int ko = (lane >> 4) * 8;

    f32x4 acc[4][4] = {};

    float4 ca[2][4], cb[2][4];
    #pragma unroll
    for (int q = 0; q < 4; ++q) {
        ca[0][q] = *(const float4*)(pa + 4 * q);
        cb[0][q] = *(const float4*)(pb + 4 * q);
        ca[1][q] = *(const float4*)(pa + BK + 4 * q);
        cb[1][q] = *(const float4*)(pb + BK + 4 * q);
    }

    const bool do_pool = (nt == 0) && mval;
    float psum = 0.0f;

#define GSTEP(SET, CIDX)                                                          \
    {                                                                             \
        const int c_ = (CIDX);                                                    \
        if (do_pool) {                                                            \
            psum += (ca[SET][0].x + ca[SET][0].y + ca[SET][0].z + ca[SET][0].w)   \
                  + (ca[SET][1].x + ca[SET][1].y + ca[SET][1].z + ca[SET][1].w)   \
                  + (ca[SET][2].x + ca[SET][2].y + ca[SET][2].z + ca[SET][2].w)   \
                  + (ca[SET][3].x + ca[SET][3].y + ca[SET][3].z + ca[SET][3].w);  \
        }                                                                         \
        if (SET == 1) {                                                           \
            float ps2 = psum + __shfl_down(psum, 1, 64);                          \
            if (do_pool && h == 0) plocal[r][c_ >> 1] = ps2;                      \
            psum = 0.0f;                                                          \
        }                                                                         \
        _Float16* wA = &As[SET][r * LDA + h * 16];                                \
        *((uint4*)wA)     = make_uint4(                                           \
            cvt2(ca[SET][0].x, ca[SET][0].y), cvt2(ca[SET][0].z, ca[SET][0].w),   \
            cvt2(ca[SET][1].x, ca[SET][1].y), cvt2(ca[SET][1].z, ca[SET][1].w));  \
        *((uint4*)wA + 1) = make_uint4(                                           \
            cvt2(ca[SET][2].x, ca[SET][2].y), cvt2(ca[SET][2].z, ca[SET][2].w),   \
            cvt2(ca[SET][3].x, ca[SET][3].y), cvt2(ca[SET][3].z, ca[SET][3].w));  \
        _Float16* wB = &Bs[SET][r * LDA + h * 16];                                \
        *((uint4*)wB)     = make_uint4(                                           \
            cvt2(cb[SET][0].x, cb[SET][0].y), cvt2(cb[SET][0].z, cb[SET][0].w),   \
            cvt2(cb[SET][1].x, cb[SET][1].y), cvt2(cb[SET][1].z, cb[SET][1].w));  \
        *((uint4*)wB + 1) = make_uint4(                                           \
            cvt2(cb[SET][2].x, cb[SET][2].y), cvt2(cb[SET][2].z, cb[SET][2].w),   \
            cvt2(cb[SET][3].x, cb[SET][3].y), cvt2(cb[SET][3].z, cb[SET][3].w));  \
        if (c_ + 2 < NCH) {                                                       \
            const float* qa = pa + (c_ + 2) * BK;                                 \
            const float* qb = pb + (c_ + 2) * BK;                                 \
            _Pragma("unroll")                                                     \
            for (int q = 0; q < 4; ++q) {                                         \
                ca[SET][q] = *(const float4*)(qa + 4 * q);                        \
                cb[SET][q] = *(const float4*)(qb + 4 * q);                        \
            }                                                                     \
        }                                                                         \
        barrier_lgkm();                                                          \
        f16x8 af[4], bfr[4];                                                      \
        _Pragma("unroll")                                                         \
        for (int i = 0; i < 4; ++i)                                               \
            af[i] = *(const f16x8*)(&As[SET][(wr + i * 16 + fl) * LDA + ko]);     \
        _Pragma("unroll")                                                         \
        for (int j = 0; j < 4; ++j)                                               \
            bfr[j] = *(const f16x8*)(&Bs[SET][(wc + j * 16 + fl) * LDA + ko]);    \
        _Pragma("unroll")                                                         \
        for (int i = 0; i < 4; ++i)                                               \
            _Pragma("unroll")                                                     \
            for (int j = 0; j < 4; ++j)                                           \
                acc[i][j] = __builtin_amdgcn_mfma_f32_16x16x32_f16(               \
                                af[i], bfr[j], acc[i][j], 0, 0, 0);               \
    }

    for (int cc = 0; cc < NCH; cc += 2) {
        GSTEP(0, cc)
        GSTEP(1, cc + 1)
    }
#undef GSTEP

    if (nt == 0) {
        __syncthreads();
        for (int idx = t; idx < BM * (NCH / 2); idx += 256) {
            const int rr = idx / (NCH / 2), j = idx % (NCH / 2);
            const int g = mt * BM + rr;
            if (g < Mz) atomicAdd(&pooled[(g / Vz) * Dz + s * (NCH / 2) + j], plocal[rr][j]);
        }
    }

    const int rq = (lane >> 4) * 4;
    float* dst = PART ? (part + (size_t)s * Mz * Nz) : C;
    #pragma unroll
    for (int i = 0; i < 4; ++i) {
        const int gmr0 = mt * BM + wr + i * 16 + rq;
        #pragma unroll
        for (int j = 0; j < 4; ++j) {
            const int gnc = nt * BN + wc + j * 16 + fl;
            if (gnc < Nz) {
                #pragma unroll
                for (int q2 = 0; q2 < 4; ++q2) {
                    const int gmr = gmr0 + q2;
                    if (gmr < Mz) {
                        if (PART) dst[(size_t)gmr * Nz + gnc] = acc[i][j][q2];
                        else      atomicAdd(&dst[(size_t)gmr * Nz + gnc], acc[i][j][q2]);
                    }
                }
            }
        }
    }
}

// ===================== x-only fp32 -> fp16 convert (dense sliding front) =======
// 10752 chunks of 2048 floats; block b handles chunks b, b+1344, ... (8 steps,
// exact). W conversion is gone — the GEMM consumes Wb/lA fp32 directly.
__global__ __launch_bounds__(256)
void convert_kernel(const float* __restrict__ x, _Float16* __restrict__ xh,
                    float* __restrict__ ppart)
{
    const int t = threadIdx.x;
    for (int g = blockIdx.x; g < CVTOT; g += CVNB) {
        const int row = g >> 4;            // 16 chunks per row
        const int kk  = g & 15;
        const int off = kk * CVCH + t * 8;
        const float* src  = x  + (size_t)row * Kz;
        _Float16*    dstp = xh + (size_t)row * Kz;
        const float4 u = *(const float4*)(src + off);
        const float4 v = *(const float4*)(src + off + 4);
        *(uint4*)(dstp + off) = make_uint4(cvt2(u.x, u.y), cvt2(u.z, u.w),
                                           cvt2(v.x, v.y), cvt2(v.z, v.w));
        // 8 consecutive floats per thread; 8 consecutive lanes = one d (64 p)
        float sp = (u.x + u.y + u.z + u.w) + (v.x + v.y + v.z + v.w);
        sp += __shfl_xor(sp, 1, 64);
        sp += __shfl_xor(sp, 2, 64);
        sp += __shfl_xor(sp, 4, 64);
        if ((t & 7) == 0)
            ppart[(size_t)row * Dz + kk * 32 + (t >> 3)] = sp;
    }
}

// ===================== f16 GEMM: A via LDS-DMA from xh, B fp32->f16 in-kernel ==
// A: gload16 ring (pre-swizzled source k-slot ccs). B: register-staged fp32
// loads (2xdwordx4) -> cvt_pkrtz -> ds_write_b128 into the SAME LDS layout the
// old DMA produced (addr = sB + row*32 + cc*8, content from slot ccs), deferred
// one step (T14): at step c, issue chunk c+2 loads, vmcnt(4) retires chunk c+1
// -> cvt+write B(c+1). Top barrier carries lgkmcnt(0) only (own vmcnt already
// guaranteed own A-DMA landed; barrier publishes).
__global__ __launch_bounds__(512, 4)
void gemm_f16_kernel(const _Float16* __restrict__ xh, const float* __restrict__ Wb,
                     const float* __restrict__ lA, float* __restrict__ part)
{
    __shared__ _Float16 sm[3 * SLOT];   // 72 KB -> 2 blocks/CU, 16 waves/CU

    const int id = blockIdx.x;          // 0..671
    const int x8 = id & 7;              // XCD cohort
    const int k8 = id >> 3;             // 0..83
    const int nt = k8 % 7;
    const int mt = (k8 / 7) % 3;
    const int s  = (k8 / 21) * 8 + x8;  // 0..31

    const int t = threadIdx.x;
    const int wave = t >> 6, lane = t & 63;
    const int rl = lane >> 2, cc = lane & 3;
    const int ccs = cc ^ (rl & 3);      // pre-swizzled k-slot (involution per row)

    const size_t kb = (size_t)s * KSL2;

    const int rA0 = (wave)     * 16 + rl;        // A rows 0..127
    const int rA1 = (8 + wave) * 16 + rl;        // A rows 128..255
    const int rB  = wave * 16 + rl;              // B rows 0..127
    const _Float16* gA0 = xh + (size_t)min(mt * BM2 + rA0, Mz - 1) * Kz + kb + ccs * 8;
    const _Float16* gA1 = xh + (size_t)min(mt * BM2 + rA1, Mz - 1) * Kz + kb + ccs * 8;
    const int gn = min(nt * BN2 + rB, Nz - 1);
    const float* gBf = ((gn < OUTz) ? (Wb + (size_t)gn * Kz)
                                    : (lA + (size_t)(gn - OUTz) * Kz)) + kb + ccs * 8;

    const int wr = (wave >> 1) * 64;    // 0,64,128,192
    const int wc = (wave & 1) * 64;     // 0,64
    const int fl = lane & 15;
    const int slA = ((lane >> 4) ^ (fl & 3)) * 8;   // swizzled slot, halves

    float4 bEv[2], bOd[2];              // B double-buffer (named, static idx)

    // prologue: chunk0 + chunk1 in flight (4 vm ops each: A,A,B,B)
    {
        _Float16* sA = sm;
        gload16(gA0, sA + wave * 512);
        gload16(gA1, sA + (8 + wave) * 512);
        bEv[0] = *(const float4*)(gBf);
        bEv[1] = *(const float4*)(gBf + 4);
    }
    {
        _Float16* sA = sm + SLOT;
        gload16(gA0 + BK2, sA + wave * 512);
        gload16(gA1 + BK2, sA + (8 + wave) * 512);
        bOd[0] = *(const float4*)(gBf + BK2);
        bOd[1] = *(const float4*)(gBf + BK2 + 4);
    }
    asm volatile("s_waitcnt vmcnt(4)" ::: "memory");   // chunk0 retired
    *(uint4*)(sm + ABUF + rB * 32 + cc * 8) = make_uint4(
        cvt2(bEv[0].x, bEv[0].y), cvt2(bEv[0].z, bEv[0].w),
        cvt2(bEv[1].x, bEv[1].y), cvt2(bEv[1].z, bEv[1].w));

    f32x4 acc[4][4] = {};

#define FSTEP(C_, BI, BC)                                                        \
    {                                                                            \
        barrier_lgkm();                                                          \
        if ((C_) + 2 < NCH2) {                                                   \
            _Float16* sA = sm + (((C_) + 2) % 3) * SLOT;                         \
            const size_t ko_ = (size_t)((C_) + 2) * BK2;                         \
            gload16(gA0 + ko_, sA + wave * 512);                                 \
            gload16(gA1 + ko_, sA + (8 + wave) * 512);                           \
            BI[0] = *(const float4*)(gBf + ko_);                                 \
            BI[1] = *(const float4*)(gBf + ko_ + 4);                             \
        }                                                                        \
        if ((C_) + 1 < NCH2) {                                                   \
            if ((C_) + 2 < NCH2) asm volatile("s_waitcnt vmcnt(4)" ::: "memory");\
            else                 asm volatile("s_waitcnt vmcnt(0)" ::: "memory");\
            _Float16* sB = sm + (((C_) + 1) % 3) * SLOT + ABUF;                  \
            *(uint4*)(sB + rB * 32 + cc * 8) = make_uint4(                       \
                cvt2(BC[0].x, BC[0].y), cvt2(BC[0].z, BC[0].w),                  \
                cvt2(BC[1].x, BC[1].y), cvt2(BC[1].z, BC[1].w));                 \
        }                                                                        \
        const _Float16* A  = sm + ((C_) % 3) * SLOT;                             \
        const _Float16* Bp = A + ABUF;                                           \
        f16x8 af[4], bfr[4];                                                     \
        _Pragma("unroll")                                                        \
        for (int i = 0; i < 4; ++i)                                              \
            af[i] = *(const f16x8*)(A + (wr + i * 16 + fl) * BK2 + slA);         \
        _Pragma("unroll")                                                        \
        for (int j = 0; j < 4; ++j)                                              \
            bfr[j] = *(const f16x8*)(Bp + (wc + j * 16 + fl) * BK2 + slA);       \
        _Pragma("unroll")                                                        \
        for (int i = 0; i < 4; ++i)                                              \
            _Pragma("unroll")                                                    \
            for (int j = 0; j < 4; ++j)                                          \
                acc[i][j] = __builtin_amdgcn_mfma_f32_16x16x32_f16(              \
                                af[i], bfr[j], acc[i][j], 0, 0, 0);              \
    }

    for (int c = 0; c < NCH2; c += 2) {
        FSTEP(c,     bEv, bOd)    // issue even chunk c+2 -> bEv; write odd c+1 from bOd
        FSTEP(c + 1, bOd, bEv)    // issue odd  chunk c+3 -> bOd; write even c+2 from bEv
    }
#undef FSTEP

    // split-K epilogue: C/D layout col=lane&15, row=(lane>>4)*4+reg
    const int rq = (lane >> 4) * 4;
    float* dst = part + (size_t)s * Mz * Nz;
    #pragma unroll
    for (int i = 0; i < 4; ++i) {
        const int gmr0 = mt * BM2 + wr + i * 16 + rq;
        #pragma unroll
        for (int j = 0; j < 4; ++j) {
            const int gnc = nt * BN2 + wc + j * 16 + fl;
            if (gnc < Nz) {
                #pragma unroll
                for (int q2 = 0; q2 < 4; ++q2) {
                    const int gmr = gmr0 + q2;
                    if (gmr < Mz) dst[(size_t)gmr * Nz + gnc] = acc[i][j][q2];
                }
            }
        }
    }
}

// ===================== router =====================
// PP=true: src is ppart[Mz][Dz] per-row partials (sum over v here).
// PP=false: src is pooled[Bz][Dz] raw sums (fallback paths).
template <bool PP>
__global__ __launch_bounds__(256)
void router_kernel(const float* __restrict__ src,
                   const float* __restrict__ Wr1, const float* __restrict__ br1,
                   const float* __restrict__ Wr2, const float* __restrict__ br2,
                   float* __restrict__ probs_out, int* __restrict__ tki, float* __restrict__ tkw)
{
    const int b = blockIdx.x, t = threadIdx.x;
    const int wave = t >> 6, lane = t & 63;
    __shared__ float hbuf[Hz];
    __shared__ float lg[Ez];

    const float sc = 1.0f / (float)(Vz * Pz);
    float pv[8];
    if (PP) {
        float a[8] = {0.f, 0.f, 0.f, 0.f, 0.f, 0.f, 0.f, 0.f};
        #pragma unroll
        for (int v = 0; v < Vz; ++v) {
            const float* pr = src + (size_t)(b * Vz + v) * Dz + lane * 8;
            float4 q0 = *(const float4*)pr;
            float4 q1 = *(const float4*)(pr + 4);
            a[0] += q0.x; a[1] += q0.y; a[2] += q0.z; a[3] += q0.w;
            a[4] += q1.x; a[5] += q1.y; a[6] += q1.z; a[7] += q1.w;
        }
        #pragma unroll
        for (int u = 0; u < 8; ++u) pv[u] = a[u] * sc;
    } else {
        const float* prow = src + b * Dz + lane * 8;
        #pragma unroll
        for (int u = 0; u < 8; ++u) pv[u] = prow[u] * sc;
    }

    for (int i0 = 0; i0 < 64; i0 += 4) {
        float v[4];
        #pragma unroll
        for (int u = 0; u < 4; ++u) {
            const int j = wave * 64 + i0 + u;
            const float* wrow = Wr1 + (size_t)j * Dz + lane * 8;
            float4 w0 = *(const float4*)(wrow);
            float4 w1 = *(const float4*)(wrow + 4);
            v[u] = pv[0]*w0.x + pv[1]*w0.y + pv[2]*w0.z + pv[3]*w0.w
                 + pv[4]*w1.x + pv[5]*w1.y + pv[6]*w1.z + pv[7]*w1.w;
        }
        #pragma unroll
        for (int u = 0; u < 4; ++u) {
            #pragma unroll
            for (int off = 32; off >= 1; off >>= 1) v[u] += __shfl_down(v[u], off, 64);
        }
        if (lane == 0) {
            #pragma unroll
            for (int u = 0; u < 4; ++u) {
                const int j = wave * 64 + i0 + u;
                float a = v[u] + br1[j];
                hbuf[j] = 0.5f * a * (1.0f + erff(a * 0.70710678118654752440f));
            }
        }
    }
    __syncthreads();

    if (t < Ez) {
        const float* w = Wr2 + (size_t)t * Hz;
        float a = br2[t];
        for (int j = 0; j < Hz; ++j) a = fmaf(hbuf[j], w[j], a);
        lg[t] = a;
    }
    __syncthreads();

    if (t == 0) {
        float mx = lg[0];
        for (int e = 1; e < Ez; ++e) mx = fmaxf(mx, lg[e]);
        float p[Ez], ssum = 0.0f;
        for (int e = 0; e < Ez; ++e) { p[e] = expf(lg[e] - mx); ssum += p[e]; }
        const float inv = 1.0f / ssum;
        for (int e = 0; e < Ez; ++e) { p[e] *= inv; probs_out[b * Ez + e] = p[e]; }
        int i0 = 0;
        for (int e = 1; e < Ez; ++e) if (p[e] > p[i0]) i0 = e;
        int i1 = (i0 == 0) ? 1 : 0;
        for (int e = 0; e < Ez; ++e) if (e != i0 && p[e] > p[i1]) i1 = e;
        float s2 = p[i0] + p[i1];
        if (s2 < 1e-6f) s2 = 1e-6f;
        tki[b * 2] = i0; tki[b * 2 + 1] = i1;
        tkw[b * 2] = p[i0] / s2; tkw[b * 2 + 1] = p[i1] / s2;
    }
}

// ===================== combine (+split-K reduce when PART) =====================
template <bool PART, int SPL>
__global__ __launch_bounds__(256)
void combine_kernel(const float* __restrict__ part, const float* __restrict__ C,
                    const float* __restrict__ bb, const float* __restrict__ loraB,
                    const int* __restrict__ tki, const float* __restrict__ tkw,
                    float* __restrict__ out)
{
    const int m = blockIdx.x;
    const int t = threadIdx.x;
    const int b = m / Vz;
    const int e0 = tki[b * 2], e1 = tki[b * 2 + 1];
    const float w0 = tkw[b * 2], w1 = tkw[b * 2 + 1];

    __shared__ float lw[2 * Rz];
    if (t < 2 * Rz) {
        const int e = (t < Rz) ? e0 : e1;
        const size_t off = (size_t)m * Nz + OUTz + e * Rz + (t & (Rz - 1));
        float v = 0.0f;
        if (PART) {
            #pragma unroll
            for (int ss = 0; ss < SPL; ++ss) v += part[(size_t)ss * Mz * Nz + off];
        } else v = C[off];
        lw[t] = v;
    }
    __syncthreads();

    for (int o = t; o < OUTz; o += 256) {
        float acc = bb[o];
        if (PART) {
            #pragma unroll
            for (int ss = 0; ss < SPL; ++ss)
                acc += part[(size_t)ss * Mz * Nz + (size_t)m * Nz + o];
        } else acc += C[(size_t)m * Nz + o];
        const float* B0 = loraB + ((size_t)e0 * OUTz + o) * Rz;
        const float* B1 = loraB + ((size_t)e1 * OUTz + o) * Rz;
        float d0 = 0.0f, d1 = 0.0f;
        #pragma unroll
        for (int rr = 0; rr < Rz; ++rr) {
            d0 = fmaf(lw[rr], B0[rr], d0);
            d1 = fmaf(lw[Rz + rr], B1[rr], d1);
        }
        out[(size_t)m * OUTz + o] = acc + w0 * d0 + w1 * d1;
    }
}

// ===================== launch =====================
extern "C" void kernel_launch(void* const* d_in, const int* in_sizes, int n_in,
                              void* d_out, int out_size, void* d_ws, size_t ws_size,
                              hipStream_t stream)
{
    const float* x   = (const float*)d_in[0];
    const float* Wb  = (const float*)d_in[1];
    const float* bb  = (const float*)d_in[2];
    const float* Wr1 = (const float*)d_in[3];
    const float* br1 = (const float*)d_in[4];
    const float* Wr2 = (const float*)d_in[5];
    const float* br2 = (const float*)d_in[6];
    const float* lA  = (const float*)d_in[7];
    const float* lB  = (const float*)d_in[8];
    float* out = (float*)d_out;

    // fast path: x f16 copy + SPLIT2 partials + per-row pool partials
    const size_t part2_elems = (size_t)SPLIT2 * Mz * Nz;        // 18.2M floats
    const size_t xh_halves   = (size_t)Mz * Kz;                 // 22.0M halves
    const size_t ppart_elems = (size_t)Mz * Dz;                 // 344K floats
    const size_t need_fast = part2_elems * sizeof(float)
                           + xh_halves * sizeof(_Float16)
                           + ppart_elems * sizeof(float) + 1024;

    const size_t part_elems = (size_t)SPLIT * Mz * Nz;
    const size_t need_old = (part_elems + Bz * Dz + 256) * sizeof(float);

    if (ws_size >= need_fast) {
        float*    part   = (float*)d_ws;
        _Float16* xh     = (_Float16*)(part + part2_elems);
        float*    ppart  = (float*)(xh + xh_halves);
        int*      tki    = (int*)(ppart + ppart_elems);
        float*    tkw    = (float*)(tki + 2 * Bz);

        convert_kernel<<<CVNB, 256, 0, stream>>>(x, xh, ppart);
        gemm_f16_kernel<<<3 * 7 * SPLIT2, 512, 0, stream>>>(xh, Wb, lA, part);
        router_kernel<true><<<Bz, 256, 0, stream>>>(ppart, Wr1, br1, Wr2, br2,
                                                    out + (size_t)Mz * OUTz, tki, tkw);
        combine_kernel<true, SPLIT2><<<Mz, 256, 0, stream>>>(part, nullptr, bb, lB, tki, tkw, out);
    } else if (ws_size >= need_old) {
        float* part   = (float*)d_ws;
        float* pooled = part + part_elems;
        int*   tki    = (int*)(pooled + Bz * Dz);
        float* tkw    = (float*)(tki + 2 * Bz);

        (void)hipMemsetAsync(pooled, 0, Bz * Dz * sizeof(float), stream);

        gemm_pool_kernel<true><<<dim3(7 * 6 * SPLIT), 256, 0, stream>>>(
            x, Wb, lA, part, nullptr, pooled);
        router_kernel<false><<<Bz, 256, 0, stream>>>(pooled, Wr1, br1, Wr2, br2,
                                                     out + (size_t)Mz * OUTz, tki, tkw);
        combine_kernel<true, SPLIT><<<Mz, 256, 0, stream>>>(part, nullptr, bb, lB, tki, tkw, out);
    } else {
        float* C      = (float*)d_ws;
        float* pooled = C + (size_t)Mz * Nz;
        int*   tki    = (int*)(pooled + Bz * Dz);
        float* tkw    = (float*)(tki + 2 * Bz);

        (void)hipMemsetAsync(d_ws, 0, ((size_t)Mz * Nz + Bz * Dz) * sizeof(float), stream);

        gemm_pool_kernel<false><<<dim3(7 * 6 * SPLIT), 256, 0, stream>>>(
            x, Wb, lA, nullptr, C, pooled);
        router_kernel<false><<<Bz, 256, 0, stream>>>(pooled, Wr1, br1, Wr2, br2,
                                                     out + (size_t)Mz * OUTz, tki, tkw);
        combine_kernel<false, SPLIT><<<Mz, 256, 0, stream>>>(nullptr, C, bb, lB, tki, tkw, out);
    }
}

// Round 7
// 333.378 us; speedup vs baseline: 1.0922x; 1.0922x over previous
//
#include <hip/hip_runtime.h>
#include <math.h>

// ---- problem sizes ----
constexpr int Bz = 32, Vz = 21, Dz = 512, Pz = 64;
constexpr int INz = Dz * Pz;         // 32768
constexpr int OUTz = 720;
constexpr int Ez = 8, Rz = 16, Hz = 256;
constexpr int Mz = Bz * Vz;          // 672
constexpr int Nz = OUTz + Ez * Rz;   // 848
constexpr int Kz = INz;

// ---- OLD fp32-register-staged GEMM tiling (fallback path) ----
constexpr int BM = 128, BN = 128, BK = 32;
constexpr int SPLIT = 16;            // 7*6*16 = 672 blocks
constexpr int KSL = Kz / SPLIT;      // 2048
constexpr int NCH = KSL / BK;        // 64
constexpr int LDA = 36;

// ---- f16 fused GEMM tiling (fast path) ----
constexpr int BM2 = 256, BN2 = 128, BK2 = 32;
constexpr int SPLIT2 = 16;           // grid = 3*7*16 = 336
constexpr int KSL2 = Kz / SPLIT2;    // 2048
constexpr int NCH2 = KSL2 / BK2;     // 64 (even)
constexpr int ABUF = BM2 * BK2;      // 8192 halves = 16 KB
constexpr int BBUF = BN2 * BK2;      // 4096 halves = 8 KB
constexpr int SLOT = ABUF + BBUF;    // 24 KB per ring slot, ring of 3 = 72 KB

// ---- dense-front x-only convert decomposition ----
constexpr int CVNB  = 1344;                 // blocks
constexpr int CVCH  = 2048;                 // floats per chunk (8 KB)
constexpr int CVTOT = Mz * (Kz / CVCH);     // 10752 = 1344 * 8 exactly

typedef _Float16 f16x8 __attribute__((ext_vector_type(8)));
typedef __fp16  fp16x2 __attribute__((ext_vector_type(2)));
typedef float f32x4 __attribute__((ext_vector_type(4)));

__device__ __forceinline__ unsigned int cvt2(float a, float b) {
    fp16x2 p = __builtin_amdgcn_cvt_pkrtz(a, b);
    return __builtin_bit_cast(unsigned int, p);
}

__device__ __forceinline__ void barrier_lgkm() {
    asm volatile("s_waitcnt lgkmcnt(0)\n\ts_barrier" ::: "memory");
}

// direct global->LDS DMA, 16 B per lane; LDS dest is wave-uniform base + lane*16
__device__ __forceinline__ void gload16(const _Float16* g, _Float16* l) {
    __builtin_amdgcn_global_load_lds(
        (const __attribute__((address_space(1))) unsigned int*)g,
        (__attribute__((address_space(3))) unsigned int*)l, 16, 0, 0);
}

// ===================== OLD fused GEMM (+pooling) — fallback =====================
template <bool PART>
__global__ __launch_bounds__(256, 3)
void gemm_pool_kernel(const float* __restrict__ x, const float* __restrict__ Wb,
                      const float* __restrict__ lA, float* __restrict__ part,
                      float* __restrict__ C, float* __restrict__ pooled)
{
    __shared__ _Float16 As[2][BM * LDA];
    __shared__ _Float16 Bs[2][BN * LDA];
    __shared__ float plocal[BM][NCH / 2];

    const int id = blockIdx.x;
    const int x8 = id & 7;
    const int k8 = id >> 3;
    const int nt = k8 % 7;
    const int mt = (k8 / 7) % 6;
    const int s  = (k8 / 42) * 8 + x8;

    const int t  = threadIdx.x;
    const int r  = t >> 1;
    const int h  = t & 1;
    const int kbase = s * KSL + h * 16;

    int gm = mt * BM + r;
    const bool mval = (gm < Mz);
    if (!mval) gm = Mz - 1;
    const float* pa = x + (size_t)gm * Kz + kbase;

    int gn = nt * BN + r;
    if (gn >= Nz) gn = Nz - 1;
    const float* pb = (gn < OUTz) ? (Wb + (size_t)gn * Kz + kbase)
                                  : (lA + (size_t)(gn - OUTz) * Kz + kbase);

    const int wave = t >> 6, lane = t & 63;
    const int wr = (wave >> 1) * 64;
    const int wc = (wave & 1) * 64;
    const int fl = lane & 15;
    const int ko = (lane >> 4) * 8;

    f32x4 acc[4][4] = {};

    float4 ca[2][4], cb[2][4];
    #pragma unroll
    for (int q = 0; q < 4; ++q) {
        ca[0][q] = *(const float4*)(pa + 4 * q);
        cb[0][q] = *(const float4*)(pb + 4 * q);
        ca[1][q] = *(const float4*)(pa + BK + 4 * q);
        cb[1][q] = *(const float4*)(pb + BK + 4 * q);
    }

    const bool do_pool = (nt == 0) && mval;
    float psum = 0.0f;

#define GSTEP(SET, CIDX)                                                          \
    {                                                                             \
        const int c_ = (CIDX);                                                    \
        if (do_pool) {                                                            \
            psum += (ca[SET][0].x + ca[SET][0].y + ca[SET][0].z + ca[SET][0].w)   \
                  + (ca[SET][1].x + ca[SET][1].y + ca[SET][1].z + ca[SET][1].w)   \
                  + (ca[SET][2].x + ca[SET][2].y + ca[SET][2].z + ca[SET][2].w)   \
                  + (ca[SET][3].x + ca[SET][3].y + ca[SET][3].z + ca[SET][3].w);  \
        }                                                                         \
        if (SET == 1) {                                                           \
            float ps2 = psum + __shfl_down(psum, 1, 64);                          \
            if (do_pool && h == 0) plocal[r][c_ >> 1] = ps2;                      \
            psum = 0.0f;                                                          \
        }                                                                         \
        _Float16* wA = &As[SET][r * LDA + h * 16];                                \
        *((uint4*)wA)     = make_uint4(                                           \
            cvt2(ca[SET][0].x, ca[SET][0].y), cvt2(ca[SET][0].z, ca[SET][0].w),   \
            cvt2(ca[SET][1].x, ca[SET][1].y), cvt2(ca[SET][1].z, ca[SET][1].w));  \
        *((uint4*)wA + 1) = make_uint4(                                           \
            cvt2(ca[SET][2].x, ca[SET][2].y), cvt2(ca[SET][2].z, ca[SET][2].w),   \
            cvt2(ca[SET][3].x, ca[SET][3].y), cvt2(ca[SET][3].z, ca[SET][3].w));  \
        _Float16* wB = &Bs[SET][r * LDA + h * 16];                                \
        *((uint4*)wB)     = make_uint4(                                           \
            cvt2(cb[SET][0].x, cb[SET][0].y), cvt2(cb[SET][0].z, cb[SET][0].w),   \
            cvt2(cb[SET][1].x, cb[SET][1].y), cvt2(cb[SET][1].z, cb[SET][1].w));  \
        *((uint4*)wB + 1) = make_uint4(                                           \
            cvt2(cb[SET][2].x, cb[SET][2].y), cvt2(cb[SET][2].z, cb[SET][2].w),   \
            cvt2(cb[SET][3].x, cb[SET][3].y), cvt2(cb[SET][3].z, cb[SET][3].w));  \
        if (c_ + 2 < NCH) {                                                       \
            const float* qa = pa + (c_ + 2) * BK;                                 \
            const float* qb = pb + (c_ + 2) * BK;                                 \
            _Pragma("unroll")                                                     \
            for (int q = 0; q < 4; ++q) {                                         \
                ca[SET][q] = *(const float4*)(qa + 4 * q);                        \
                cb[SET][q] = *(const float4*)(qb + 4 * q);                        \
            }                                                                     \
        }                                                                         \
        barrier_lgkm();                                                          \
        f16x8 af[4], bfr[4];                                                      \
        _Pragma("unroll")                                                         \
        for (int i = 0; i < 4; ++i)                                               \
            af[i] = *(const f16x8*)(&As[SET][(wr + i * 16 + fl) * LDA + ko]);     \
        _Pragma("unroll")                                                         \
        for (int j = 0; j < 4; ++j)                                               \
            bfr[j] = *(const f16x8*)(&Bs[SET][(wc + j * 16 + fl) * LDA + ko]);    \
        _Pragma("unroll")                                                         \
        for (int i = 0; i < 4; ++i)                                               \
            _Pragma("unroll")                                                     \
            for (int j = 0; j < 4; ++j)                                           \
                acc[i][j] = __builtin_amdgcn_mfma_f32_16x16x32_f16(               \
                                af[i], bfr[j], acc[i][j], 0, 0, 0);               \
    }

    for (int cc = 0; cc < NCH; cc += 2) {
        GSTEP(0, cc)
        GSTEP(1, cc + 1)
    }
#undef GSTEP

    if (nt == 0) {
        __syncthreads();
        for (int idx = t; idx < BM * (NCH / 2); idx += 256) {
            const int rr = idx / (NCH / 2), j = idx % (NCH / 2);
            const int g = mt * BM + rr;
            if (g < Mz) atomicAdd(&pooled[(g / Vz) * Dz + s * (NCH / 2) + j], plocal[rr][j]);
        }
    }

    const int rq = (lane >> 4) * 4;
    float* dst = PART ? (part + (size_t)s * Mz * Nz) : C;
    #pragma unroll
    for (int i = 0; i < 4; ++i) {
        const int gmr0 = mt * BM + wr + i * 16 + rq;
        #pragma unroll
        for (int j = 0; j < 4; ++j) {
            const int gnc = nt * BN + wc + j * 16 + fl;
            if (gnc < Nz) {
                #pragma unroll
                for (int q2 = 0; q2 < 4; ++q2) {
                    const int gmr = gmr0 + q2;
                    if (gmr < Mz) {
                        if (PART) dst[(size_t)gmr * Nz + gnc] = acc[i][j][q2];
                        else      atomicAdd(&dst[(size_t)gmr * Nz + gnc], acc[i][j][q2]);
                    }
                }
            }
        }
    }
}

// ===================== x-only fp32 -> fp16 convert (dense sliding front) =======
__global__ __launch_bounds__(256)
void convert_kernel(const float* __restrict__ x, _Float16* __restrict__ xh,
                    float* __restrict__ ppart)
{
    const int t = threadIdx.x;
    for (int g = blockIdx.x; g < CVTOT; g += CVNB) {
        const int row = g >> 4;            // 16 chunks per row
        const int kk  = g & 15;
        const int off = kk * CVCH + t * 8;
        const float* src  = x  + (size_t)row * Kz;
        _Float16*    dstp = xh + (size_t)row * Kz;
        const float4 u = *(const float4*)(src + off);
        const float4 v = *(const float4*)(src + off + 4);
        *(uint4*)(dstp + off) = make_uint4(cvt2(u.x, u.y), cvt2(u.z, u.w),
                                           cvt2(v.x, v.y), cvt2(v.z, v.w));
        float sp = (u.x + u.y + u.z + u.w) + (v.x + v.y + v.z + v.w);
        sp += __shfl_xor(sp, 1, 64);
        sp += __shfl_xor(sp, 2, 64);
        sp += __shfl_xor(sp, 4, 64);
        if ((t & 7) == 0)
            ppart[(size_t)row * Dz + kk * 32 + (t >> 3)] = sp;
    }
}

// ===================== f16 GEMM: A via LDS-DMA, B fp32->f16 fused ==============
// Pipeline order fixed vs prior round: per step, {barrier -> issue c+2 ->
// ds_read+MFMA chunk c -> vmcnt(4) [c+1 retired] -> ds_write B(c+1)}.
// The wait now sits AFTER the compute, so chunk-(c+1) global latency hides
// under chunk-c MFMA instead of blocking it.
__global__ __launch_bounds__(512, 4)
void gemm_f16_kernel(const _Float16* __restrict__ xh, const float* __restrict__ Wb,
                     const float* __restrict__ lA, float* __restrict__ part)
{
    __shared__ _Float16 sm[3 * SLOT];   // 72 KB -> 2 blocks/CU

    const int id = blockIdx.x;          // 0..335
    const int x8 = id & 7;              // XCD cohort
    const int k8 = id >> 3;             // 0..41
    const int nt = k8 % 7;
    const int mt = (k8 / 7) % 3;
    const int s  = (k8 / 21) * 8 + x8;  // 0..15

    const int t = threadIdx.x;
    const int wave = t >> 6, lane = t & 63;
    const int rl = lane >> 2, cc = lane & 3;
    const int ccs = cc ^ (rl & 3);      // pre-swizzled k-slot (involution per row)

    const size_t kb = (size_t)s * KSL2;

    const int rA0 = (wave)     * 16 + rl;        // A rows 0..127
    const int rA1 = (8 + wave) * 16 + rl;        // A rows 128..255
    const int rB  = wave * 16 + rl;              // B rows 0..127
    const _Float16* gA0 = xh + (size_t)min(mt * BM2 + rA0, Mz - 1) * Kz + kb + ccs * 8;
    const _Float16* gA1 = xh + (size_t)min(mt * BM2 + rA1, Mz - 1) * Kz + kb + ccs * 8;
    const int gn = min(nt * BN2 + rB, Nz - 1);
    const float* gBf = ((gn < OUTz) ? (Wb + (size_t)gn * Kz)
                                    : (lA + (size_t)(gn - OUTz) * Kz)) + kb + ccs * 8;

    const int wr = (wave >> 1) * 64;    // 0,64,128,192
    const int wc = (wave & 1) * 64;     // 0,64
    const int fl = lane & 15;
    const int slA = ((lane >> 4) ^ (fl & 3)) * 8;   // swizzled slot, halves

    float4 bEv[2], bOd[2];              // B double-buffer (named, static idx)

    // prologue: chunk0 + chunk1 in flight (4 vm ops each: A,A,B,B)
    {
        _Float16* sA = sm;
        gload16(gA0, sA + wave * 512);
        gload16(gA1, sA + (8 + wave) * 512);
        bEv[0] = *(const float4*)(gBf);
        bEv[1] = *(const float4*)(gBf + 4);
    }
    {
        _Float16* sA = sm + SLOT;
        gload16(gA0 + BK2, sA + wave * 512);
        gload16(gA1 + BK2, sA + (8 + wave) * 512);
        bOd[0] = *(const float4*)(gBf + BK2);
        bOd[1] = *(const float4*)(gBf + BK2 + 4);
    }
    asm volatile("s_waitcnt vmcnt(4)" ::: "memory");   // chunk0 retired
    *(uint4*)(sm + ABUF + rB * 32 + cc * 8) = make_uint4(
        cvt2(bEv[0].x, bEv[0].y), cvt2(bEv[0].z, bEv[0].w),
        cvt2(bEv[1].x, bEv[1].y), cvt2(bEv[1].z, bEv[1].w));

    f32x4 acc[4][4] = {};

#define FSTEP(C_, BI, BC)                                                        \
    {                                                                            \
        asm volatile("s_waitcnt lgkmcnt(0)\n\ts_barrier" ::: "memory");          \
        if ((C_) + 2 < NCH2) {                                                   \
            _Float16* sA = sm + (((C_) + 2) % 3) * SLOT;                         \
            const size_t ko_ = (size_t)((C_) + 2) * BK2;                         \
            gload16(gA0 + ko_, sA + wave * 512);                                 \
            gload16(gA1 + ko_, sA + (8 + wave) * 512);                           \
            BI[0] = *(const float4*)(gBf + ko_);                                 \
            BI[1] = *(const float4*)(gBf + ko_ + 4);                             \
        }                                                                        \
        const _Float16* A  = sm + ((C_) % 3) * SLOT;                             \
        const _Float16* Bp = A + ABUF;                                           \
        f16x8 af[4], bfr[4];                                                     \
        _Pragma("unroll")                                                        \
        for (int i = 0; i < 4; ++i)                                              \
            af[i] = *(const f16x8*)(A + (wr + i * 16 + fl) * BK2 + slA);         \
        _Pragma("unroll")                                                        \
        for (int j = 0; j < 4; ++j)                                              \
            bfr[j] = *(const f16x8*)(Bp + (wc + j * 16 + fl) * BK2 + slA);       \
        _Pragma("unroll")                                                        \
        for (int i = 0; i < 4; ++i)                                              \
            _Pragma("unroll")                                                    \
            for (int j = 0; j < 4; ++j)                                          \
                acc[i][j] = __builtin_amdgcn_mfma_f32_16x16x32_f16(              \
                                af[i], bfr[j], acc[i][j], 0, 0, 0);              \
        if ((C_) + 1 < NCH2) {                                                   \
            if ((C_) + 2 < NCH2) asm volatile("s_waitcnt vmcnt(4)" ::: "memory");\
            else                 asm volatile("s_waitcnt vmcnt(0)" ::: "memory");\
            _Float16* sB = sm + (((C_) + 1) % 3) * SLOT + ABUF;                  \
            *(uint4*)(sB + rB * 32 + cc * 8) = make_uint4(                       \
                cvt2(BC[0].x, BC[0].y), cvt2(BC[0].z, BC[0].w),                  \
                cvt2(BC[1].x, BC[1].y), cvt2(BC[1].z, BC[1].w));                 \
        }                                                                        \
    }

    for (int c = 0; c < NCH2; c += 2) {
        FSTEP(c,     bEv, bOd)    // issue even chunk c+2 -> bEv; write B(c+1) from bOd
        FSTEP(c + 1, bOd, bEv)    // issue odd  chunk c+3 -> bOd; write B(c+2) from bEv
    }
#undef FSTEP

    // split-K epilogue: C/D layout col=lane&15, row=(lane>>4)*4+reg
    const int rq = (lane >> 4) * 4;
    float* dst = part + (size_t)s * Mz * Nz;
    #pragma unroll
    for (int i = 0; i < 4; ++i) {
        const int gmr0 = mt * BM2 + wr + i * 16 + rq;
        #pragma unroll
        for (int j = 0; j < 4; ++j) {
            const int gnc = nt * BN2 + wc + j * 16 + fl;
            if (gnc < Nz) {
                #pragma unroll
                for (int q2 = 0; q2 < 4; ++q2) {
                    const int gmr = gmr0 + q2;
                    if (gmr < Mz) dst[(size_t)gmr * Nz + gnc] = acc[i][j][q2];
                }
            }
        }
    }
}

// ===================== router =====================
template <bool PP>
__global__ __launch_bounds__(256)
void router_kernel(const float* __restrict__ src,
                   const float* __restrict__ Wr1, const float* __restrict__ br1,
                   const float* __restrict__ Wr2, const float* __restrict__ br2,
                   float* __restrict__ probs_out, int* __restrict__ tki, float* __restrict__ tkw)
{
    const int b = blockIdx.x, t = threadIdx.x;
    const int wave = t >> 6, lane = t & 63;
    __shared__ float hbuf[Hz];
    __shared__ float lg[Ez];

    const float sc = 1.0f / (float)(Vz * Pz);
    float pv[8];
    if (PP) {
        float a[8] = {0.f, 0.f, 0.f, 0.f, 0.f, 0.f, 0.f, 0.f};
        #pragma unroll
        for (int v = 0; v < Vz; ++v) {
            const float* pr = src + (size_t)(b * Vz + v) * Dz + lane * 8;
            float4 q0 = *(const float4*)pr;
            float4 q1 = *(const float4*)(pr + 4);
            a[0] += q0.x; a[1] += q0.y; a[2] += q0.z; a[3] += q0.w;
            a[4] += q1.x; a[5] += q1.y; a[6] += q1.z; a[7] += q1.w;
        }
        #pragma unroll
        for (int u = 0; u < 8; ++u) pv[u] = a[u] * sc;
    } else {
        const float* prow = src + b * Dz + lane * 8;
        #pragma unroll
        for (int u = 0; u < 8; ++u) pv[u] = prow[u] * sc;
    }

    for (int i0 = 0; i0 < 64; i0 += 4) {
        float v[4];
        #pragma unroll
        for (int u = 0; u < 4; ++u) {
            const int j = wave * 64 + i0 + u;
            const float* wrow = Wr1 + (size_t)j * Dz + lane * 8;
            float4 w0 = *(const float4*)(wrow);
            float4 w1 = *(const float4*)(wrow + 4);
            v[u] = pv[0]*w0.x + pv[1]*w0.y + pv[2]*w0.z + pv[3]*w0.w
                 + pv[4]*w1.x + pv[5]*w1.y + pv[6]*w1.z + pv[7]*w1.w;
        }
        #pragma unroll
        for (int u = 0; u < 4; ++u) {
            #pragma unroll
            for (int off = 32; off >= 1; off >>= 1) v[u] += __shfl_down(v[u], off, 64);
        }
        if (lane == 0) {
            #pragma unroll
            for (int u = 0; u < 4; ++u) {
                const int j = wave * 64 + i0 + u;
                float a = v[u] + br1[j];
                hbuf[j] = 0.5f * a * (1.0f + erff(a * 0.70710678118654752440f));
            }
        }
    }
    __syncthreads();

    if (t < Ez) {
        const float* w = Wr2 + (size_t)t * Hz;
        float a = br2[t];
        for (int j = 0; j < Hz; ++j) a = fmaf(hbuf[j], w[j], a);
        lg[t] = a;
    }
    __syncthreads();

    if (t == 0) {
        float mx = lg[0];
        for (int e = 1; e < Ez; ++e) mx = fmaxf(mx, lg[e]);
        float p[Ez], ssum = 0.0f;
        for (int e = 0; e < Ez; ++e) { p[e] = expf(lg[e] - mx); ssum += p[e]; }
        const float inv = 1.0f / ssum;
        for (int e = 0; e < Ez; ++e) { p[e] *= inv; probs_out[b * Ez + e] = p[e]; }
        int i0 = 0;
        for (int e = 1; e < Ez; ++e) if (p[e] > p[i0]) i0 = e;
        int i1 = (i0 == 0) ? 1 : 0;
        for (int e = 0; e < Ez; ++e) if (e != i0 && p[e] > p[i1]) i1 = e;
        float s2 = p[i0] + p[i1];
        if (s2 < 1e-6f) s2 = 1e-6f;
        tki[b * 2] = i0; tki[b * 2 + 1] = i1;
        tkw[b * 2] = p[i0] / s2; tkw[b * 2 + 1] = p[i1] / s2;
    }
}

// ===================== combine (+split-K reduce when PART) =====================
template <bool PART, int SPL>
__global__ __launch_bounds__(256)
void combine_kernel(const float* __restrict__ part, const float* __restrict__ C,
                    const float* __restrict__ bb, const float* __restrict__ loraB,
                    const int* __restrict__ tki, const float* __restrict__ tkw,
                    float* __restrict__ out)
{
    const int m = blockIdx.x;
    const int t = threadIdx.x;
    const int b = m / Vz;
    const int e0 = tki[b * 2], e1 = tki[b * 2 + 1];
    const float w0 = tkw[b * 2], w1 = tkw[b * 2 + 1];

    __shared__ float lw[2 * Rz];
    if (t < 2 * Rz) {
        const int e = (t < Rz) ? e0 : e1;
        const size_t off = (size_t)m * Nz + OUTz + e * Rz + (t & (Rz - 1));
        float v = 0.0f;
        if (PART) {
            #pragma unroll
            for (int ss = 0; ss < SPL; ++ss) v += part[(size_t)ss * Mz * Nz + off];
        } else v = C[off];
        lw[t] = v;
    }
    __syncthreads();

    for (int o = t; o < OUTz; o += 256) {
        float acc = bb[o];
        if (PART) {
            #pragma unroll
            for (int ss = 0; ss < SPL; ++ss)
                acc += part[(size_t)ss * Mz * Nz + (size_t)m * Nz + o];
        } else acc += C[(size_t)m * Nz + o];
        const float* B0 = loraB + ((size_t)e0 * OUTz + o) * Rz;
        const float* B1 = loraB + ((size_t)e1 * OUTz + o) * Rz;
        float d0 = 0.0f, d1 = 0.0f;
        #pragma unroll
        for (int rr = 0; rr < Rz; ++rr) {
            d0 = fmaf(lw[rr], B0[rr], d0);
            d1 = fmaf(lw[Rz + rr], B1[rr], d1);
        }
        out[(size_t)m * OUTz + o] = acc + w0 * d0 + w1 * d1;
    }
}

// ===================== launch =====================
extern "C" void kernel_launch(void* const* d_in, const int* in_sizes, int n_in,
                              void* d_out, int out_size, void* d_ws, size_t ws_size,
                              hipStream_t stream)
{
    const float* x   = (const float*)d_in[0];
    const float* Wb  = (const float*)d_in[1];
    const float* bb  = (const float*)d_in[2];
    const float* Wr1 = (const float*)d_in[3];
    const float* br1 = (const float*)d_in[4];
    const float* Wr2 = (const float*)d_in[5];
    const float* br2 = (const float*)d_in[6];
    const float* lA  = (const float*)d_in[7];
    const float* lB  = (const float*)d_in[8];
    float* out = (float*)d_out;

    // fast path: x f16 copy + SPLIT2 partials + per-row pool partials
    const size_t part2_elems = (size_t)SPLIT2 * Mz * Nz;        // 9.1M floats
    const size_t xh_halves   = (size_t)Mz * Kz;                 // 22.0M halves
    const size_t ppart_elems = (size_t)Mz * Dz;                 // 344K floats
    const size_t need_fast = part2_elems * sizeof(float)
                           + xh_halves * sizeof(_Float16)
                           + ppart_elems * sizeof(float) + 1024;

    const size_t part_elems = (size_t)SPLIT * Mz * Nz;
    const size_t need_old = (part_elems + Bz * Dz + 256) * sizeof(float);

    if (ws_size >= need_fast) {
        float*    part   = (float*)d_ws;
        _Float16* xh     = (_Float16*)(part + part2_elems);
        float*    ppart  = (float*)(xh + xh_halves);
        int*      tki    = (int*)(ppart + ppart_elems);
        float*    tkw    = (float*)(tki + 2 * Bz);

        convert_kernel<<<CVNB, 256, 0, stream>>>(x, xh, ppart);
        gemm_f16_kernel<<<3 * 7 * SPLIT2, 512, 0, stream>>>(xh, Wb, lA, part);
        router_kernel<true><<<Bz, 256, 0, stream>>>(ppart, Wr1, br1, Wr2, br2,
                                                    out + (size_t)Mz * OUTz, tki, tkw);
        combine_kernel<true, SPLIT2><<<Mz, 256, 0, stream>>>(part, nullptr, bb, lB, tki, tkw, out);
    } else if (ws_size >= need_old) {
        float* part   = (float*)d_ws;
        float* pooled = part + part_elems;
        int*   tki    = (int*)(pooled + Bz * Dz);
        float* tkw    = (float*)(tki + 2 * Bz);

        (void)hipMemsetAsync(pooled, 0, Bz * Dz * sizeof(float), stream);

        gemm_pool_kernel<true><<<dim3(7 * 6 * SPLIT), 256, 0, stream>>>(
            x, Wb, lA, part, nullptr, pooled);
        router_kernel<false><<<Bz, 256, 0, stream>>>(pooled, Wr1, br1, Wr2, br2,
                                                     out + (size_t)Mz * OUTz, tki, tkw);
        combine_kernel<true, SPLIT><<<Mz, 256, 0, stream>>>(part, nullptr, bb, lB, tki, tkw, out);
    } else {
        float* C      = (float*)d_ws;
        float* pooled = C + (size_t)Mz * Nz;
        int*   tki    = (int*)(pooled + Bz * Dz);
        float* tkw    = (float*)(tki + 2 * Bz);

        (void)hipMemsetAsync(d_ws, 0, ((size_t)Mz * Nz + Bz * Dz) * sizeof(float), stream);

        gemm_pool_kernel<false><<<dim3(7 * 6 * SPLIT), 256, 0, stream>>>(
            x, Wb, lA, nullptr, C, pooled);
        router_kernel<false><<<Bz, 256, 0, stream>>>(pooled, Wr1, br1, Wr2, br2,
                                                     out + (size_t)Mz * OUTz, tki, tkw);
        combine_kernel<false, SPLIT><<<Mz, 256, 0, stream>>>(nullptr, C, bb, lB, tki, tkw, out);
    }
}